// Round 8
// baseline (2399.305 us; speedup 1.0000x reference)
//
#include <hip/hip_runtime.h>
#include <hip/hip_bf16.h>

typedef __attribute__((ext_vector_type(8))) short  short8;   // 8 bf16 (4 VGPRs) MFMA frag
typedef __attribute__((ext_vector_type(4))) float  f32x4;    // MFMA accum frag

#define T_TOTAL 512
#define BATCH   64
#define EMB     512
#define RNN     1024
#define G3      3072      // 3*RNN
#define WROWS   48        // 3 gates x 16 units per WG
#define WPAD    1032      // LDS row stride (shorts): 16B-aligned, 4-bank row stagger
#define RPAD    18        // red[] batch stride (floats): max 2-way (free)
#define NWG     256
#define NGRP    4         // independent batch groups (16 batches each)
#define SMEM_BYTES (WROWS * WPAD * 2 + 4 * WROWS * RPAD * 4)   // 99072 + 13824 = 112896

// ---- bf16 helpers ----
__device__ __forceinline__ unsigned short f2bf(float f) {
    union { float f; unsigned int u; } v; v.f = f;
    unsigned int r = v.u + 0x7fffu + ((v.u >> 16) & 1u);   // round-nearest-even
    return (unsigned short)(r >> 16);
}
__device__ __forceinline__ float bf2f(unsigned short h) {
    union { unsigned int u; float f; } v; v.u = ((unsigned int)h) << 16;
    return v.f;
}
__device__ __forceinline__ float sigmoidf_(float x) { return 1.f / (1.f + __expf(-x)); }
__device__ __forceinline__ float tanhf_(float x) {
    float ax = fabsf(x);
    float e2 = __expf(-2.f * ax);
    float t  = (1.f - e2) / (1.f + e2);
    return x < 0.f ? -t : t;
}

// ============================================================================
// Per-K-quarter dataflow sync (relaxed agent-scope sc1 atomics only).
// Group has 4 arrival lines, one per unit-quarter; quarter kq's h units are
// produced by the 16 WGs sidx in [16kq,16kq+16). Producer: after the entry
// __syncthreads (h stores drained, implicit vmcnt(0)), thread0 RMWs its
// quarter line. Consumer: wave kq lane0 spins on line[kq] >= 16*ph, then the
// wave immediately issues its h loads — no WG-wide wake, skew window is 16
// producers not 64. Release/acquire from per-wave vmcnt order (payload h is
// itself sc1). Counters monotonic across launches, never reset.
// ============================================================================
__device__ __forceinline__ void qbar_arrive(unsigned int* lines, int qline) {
    __syncthreads();                         // all waves' h stores drained (vmcnt 0)
    if (threadIdx.x == 0)
        __hip_atomic_fetch_add(&lines[qline * 64], 1u,
                               __ATOMIC_RELAXED, __HIP_MEMORY_SCOPE_AGENT);
}
__device__ __forceinline__ void qbar_wave_wait(unsigned int* lines, int kq,
                                               unsigned int ph) {
    if ((threadIdx.x & 63) == 0) {           // lane0 of each wave, exec-masked spin
        while (__hip_atomic_load(&lines[kq * 64], __ATOMIC_RELAXED,
                                 __HIP_MEMORY_SCOPE_AGENT) < ph * 16u)
            __builtin_amdgcn_s_sleep(1);
    }
}

__global__ void bar_init(unsigned int* bar) {
    for (int i = threadIdx.x; i < NGRP * 256; i += 256) bar[i] = 0;
}

// ============================================================================
// K1: gi[t,b,:] = emb_table[x[t,b]] @ w_ih^T + b_ih  for nsteps starting at t0.
// Grid: (m-tiles = nsteps, n-tiles = 48). gi rows indexed LOCALLY (t - t0).
// ============================================================================
__global__ __launch_bounds__(256) void gi_kernel(
    const int* __restrict__ x, const float* __restrict__ emb,
    const float* __restrict__ w_ih, const float* __restrict__ b_ih,
    unsigned short* __restrict__ gi, int t0)
{
    __shared__ __align__(16) unsigned short Asm[64 * 40];
    __shared__ __align__(16) unsigned short Bsm[64 * 40];

    const int tid = threadIdx.x;
    const int mt = blockIdx.x;              // local timestep (64 batch rows)
    const int nt = blockIdx.y;
    const int m0 = mt * 64, n0 = nt * 64;

    const int r  = tid >> 2;
    const int c8 = (tid & 3) * 8;
    const int xi = x[t0 * BATCH + m0 + r];  // global row for the gather
    const float* arow = emb  + (size_t)xi * EMB;
    const float* brow = w_ih + (size_t)(n0 + r) * EMB;

    const int lane = tid & 63, wv = tid >> 6;
    const int m_off = (wv & 1) * 32, n_off = (wv >> 1) * 32;
    const int lr = lane & 15, lq = lane >> 4;

    f32x4 acc[2][2];
    #pragma unroll
    for (int i = 0; i < 2; ++i)
        #pragma unroll
        for (int j = 0; j < 2; ++j) acc[i][j] = (f32x4){0.f, 0.f, 0.f, 0.f};

    for (int k0 = 0; k0 < EMB; k0 += 32) {
        const float4 a0 = *(const float4*)(arow + k0 + c8);
        const float4 a1 = *(const float4*)(arow + k0 + c8 + 4);
        const float4 b0 = *(const float4*)(brow + k0 + c8);
        const float4 b1 = *(const float4*)(brow + k0 + c8 + 4);
        __syncthreads();
        short8 av, bv;
        av[0]=f2bf(a0.x); av[1]=f2bf(a0.y); av[2]=f2bf(a0.z); av[3]=f2bf(a0.w);
        av[4]=f2bf(a1.x); av[5]=f2bf(a1.y); av[6]=f2bf(a1.z); av[7]=f2bf(a1.w);
        bv[0]=f2bf(b0.x); bv[1]=f2bf(b0.y); bv[2]=f2bf(b0.z); bv[3]=f2bf(b0.w);
        bv[4]=f2bf(b1.x); bv[5]=f2bf(b1.y); bv[6]=f2bf(b1.z); bv[7]=f2bf(b1.w);
        *(short8*)&Asm[r * 40 + c8] = av;
        *(short8*)&Bsm[r * 40 + c8] = bv;
        __syncthreads();

        const short8 fa0 = *(const short8*)&Asm[(m_off + lr)      * 40 + lq * 8];
        const short8 fa1 = *(const short8*)&Asm[(m_off + 16 + lr) * 40 + lq * 8];
        const short8 fb0 = *(const short8*)&Bsm[(n_off + lr)      * 40 + lq * 8];
        const short8 fb1 = *(const short8*)&Bsm[(n_off + 16 + lr) * 40 + lq * 8];
        acc[0][0] = __builtin_amdgcn_mfma_f32_16x16x32_bf16(fa0, fb0, acc[0][0], 0, 0, 0);
        acc[0][1] = __builtin_amdgcn_mfma_f32_16x16x32_bf16(fa0, fb1, acc[0][1], 0, 0, 0);
        acc[1][0] = __builtin_amdgcn_mfma_f32_16x16x32_bf16(fa1, fb0, acc[1][0], 0, 0, 0);
        acc[1][1] = __builtin_amdgcn_mfma_f32_16x16x32_bf16(fa1, fb1, acc[1][1], 0, 0, 0);
    }

    const float bia0 = b_ih[n0 + n_off + lr];
    const float bia1 = b_ih[n0 + n_off + 16 + lr];
    #pragma unroll
    for (int mi = 0; mi < 2; ++mi)
        #pragma unroll
        for (int ni = 0; ni < 2; ++ni) {
            const int n = n0 + n_off + ni * 16 + lr;
            const float bia = ni ? bia1 : bia0;
            #pragma unroll
            for (int q = 0; q < 4; ++q) {
                const int m = m0 + m_off + mi * 16 + lq * 4 + q;
                gi[(size_t)m * G3 + n] = f2bf(acc[mi][ni][q] + bia);
            }
        }
}

// ============================================================================
// K2: recurrence over nsteps (512 fused, or 128/chunk fallback).
// WG (grp, sidx): batches b0=grp*16..+16, units j0=sidx*16..+16; w_hh slice
// 48 rows in 99 KB dynamic LDS. Waves = K quarters, each gated only by its
// quarter's 16 producers (qbar). 3 gate-tile MFMAs per k-step. h ping-pong
// bf16 sc1; h_reg f32 in-register across all steps.
// Ping-pong safety: a WG's h(t+1) stores sit behind its red-__syncthreads
// (joins all 4 waves -> all 4 lines at ph(t) -> every WG's step-t reads done).
// ============================================================================
__global__ __launch_bounds__(256, 1) void rec_kernel(
    const unsigned short* __restrict__ gi,
    const float* __restrict__ w_hh, const float* __restrict__ b_hh,
    unsigned short* __restrict__ hb0, unsigned short* __restrict__ hb1,
    float* __restrict__ hf, unsigned int* bar, int t0, int nsteps, int pbase)
{
    extern __shared__ __align__(16) char smem[];
    unsigned short* Wsm = (unsigned short*)smem;                      // 48 x WPAD
    float (*red)[WROWS][RPAD] = (float (*)[WROWS][RPAD])(smem + WROWS * WPAD * 2);

    const int tid = threadIdx.x;
    const int wg  = blockIdx.x;
    const int grp = wg & 3, sidx = wg >> 2;
    const int b0 = grp * 16, j0 = sidx * 16;
    unsigned int* lines = &bar[grp * 256];          // 4 quarter lines, 256B apart
    const int qline = sidx >> 4;                    // which quarter this WG produces

    // ---- stage w_hh slice -> LDS bf16 (rows: [gate*16+u][k]) ----
    #pragma unroll 4
    for (int it = 0; it < 48; ++it) {
        const int i   = it * 256 + tid;
        const int row = i >> 8;                     // 0..47 (256 float4 per row)
        const int c4  = (i & 255) * 4;
        const int gate = row >> 4, uu = row & 15;
        const float4 v = *(const float4*)(w_hh + (size_t)(gate * RNN + j0 + uu) * RNN + c4);
        unsigned short* dst = &Wsm[row * WPAD + c4];
        dst[0] = f2bf(v.x); dst[1] = f2bf(v.y); dst[2] = f2bf(v.z); dst[3] = f2bf(v.w);
    }

    // ---- gate-thread identity: (unit u 0..15, batch bl 0..15) ----
    const int u  = tid & 15;
    const int bl = tid >> 4;
    const int j  = j0 + u;
    const int b  = b0 + bl;
    const float bhr = b_hh[j], bhi = b_hh[RNN + j], bhn = b_hh[2 * RNN + j];

    float h_reg;
    if (t0 == 0) {
        h_reg = 0.f;
        if ((u & 1) == 0)
            __hip_atomic_store((unsigned int*)&hb0[b * RNN + j], 0u,
                               __ATOMIC_RELAXED, __HIP_MEMORY_SCOPE_AGENT);
    } else {
        h_reg = hf[b * RNN + j];            // f32 state from previous launch
    }
    qbar_arrive(lines, qline);              // initial h published (ph = pbase+1)

    // gi(t=0) prefetch (gi is locally indexed; completes under first wait)
    size_t gb = (size_t)b * G3 + j0 + u;
    float gir = bf2f(gi[gb]);
    float gii = bf2f(gi[gb + RNN]);
    float gin = bf2f(gi[gb + 2 * RNN]);

    // ---- MFMA identity: wave kq = K quarter; lr = batch col / unit row ----
    const int lane = tid & 63, kq = tid >> 6;
    const int lr = lane & 15, lq = lane >> 4;
    const unsigned short* wbase = Wsm + kq * 256 + lq * 8;
    const size_t hoff = ((size_t)(b0 + lr) * RNN + kq * 256 + lq * 8) >> 2;  // in u64s

    for (int t = 0; t < nsteps; ++t) {
        const unsigned short* hrd = (t & 1) ? hb1 : hb0;
        unsigned short*       hwr = (t & 1) ? hb0 : hb1;

        // wave-local wait on this quarter's 16 producers, then load immediately
        qbar_wave_wait(lines, kq, (unsigned)(pbase + 1 + t));

        union { unsigned long long q[2]; short8 s8; } hv[8];
        const unsigned long long* hp = (const unsigned long long*)hrd + hoff;
        #pragma unroll
        for (int ks = 0; ks < 8; ++ks) {
            hv[ks].q[0] = __hip_atomic_load(hp + ks * 8,     __ATOMIC_RELAXED,
                                            __HIP_MEMORY_SCOPE_AGENT);
            hv[ks].q[1] = __hip_atomic_load(hp + ks * 8 + 1, __ATOMIC_RELAXED,
                                            __HIP_MEMORY_SCOPE_AGENT);
        }

        f32x4 acc[3];
        acc[0] = (f32x4){0.f, 0.f, 0.f, 0.f};
        acc[1] = (f32x4){0.f, 0.f, 0.f, 0.f};
        acc[2] = (f32x4){0.f, 0.f, 0.f, 0.f};
        #pragma unroll
        for (int ks = 0; ks < 8; ++ks) {
            const int k = ks * 32;
            #pragma unroll
            for (int gt = 0; gt < 3; ++gt) {
                const short8 a = *(const short8*)(wbase + (gt * 16 + lr) * WPAD + k);
                acc[gt] = __builtin_amdgcn_mfma_f32_16x16x32_bf16(a, hv[ks].s8,
                                                                  acc[gt], 0, 0, 0);
            }
        }
        #pragma unroll
        for (int gt = 0; gt < 3; ++gt)
            #pragma unroll
            for (int q = 0; q < 4; ++q)
                red[kq][gt * 16 + lq * 4 + q][lr] = acc[gt][q];   // C: row=lq*4+q, col=lr
        __syncthreads();                     // red complete; joins all 4 waves

        const float ghr = red[0][u][bl]      + red[1][u][bl]
                        + red[2][u][bl]      + red[3][u][bl];
        const float ghi = red[0][16 + u][bl] + red[1][16 + u][bl]
                        + red[2][16 + u][bl] + red[3][16 + u][bl];
        const float ghn = red[0][32 + u][bl] + red[1][32 + u][bl]
                        + red[2][32 + u][bl] + red[3][32 + u][bl];
        const float rr = sigmoidf_(gir + ghr + bhr);
        const float zz = sigmoidf_(gii + ghi + bhi);
        const float nn = tanhf_(gin + rr * (ghn + bhn));
        h_reg = zz * nn + (1.f - zz) * h_reg;

        // packed pair store (u, u^1 share one dword), write-through sc1
        unsigned int hvv = (unsigned int)f2bf(h_reg);
        unsigned int ovv = __shfl_xor((int)hvv, 1);
        if ((u & 1) == 0)
            __hip_atomic_store((unsigned int*)&hwr[b * RNN + j],
                               hvv | (ovv << 16), __ATOMIC_RELAXED,
                               __HIP_MEMORY_SCOPE_AGENT);

        qbar_arrive(lines, qline);           // publish h(t+1) for this quarter
        // prefetch gi(t+1); completes under the next wave-wait spin
        const int tn = (t + 1 < nsteps) ? t + 1 : t;
        gb = ((size_t)tn * BATCH + b) * G3 + j0 + u;
        gir = bf2f(gi[gb]);
        gii = bf2f(gi[gb + RNN]);
        gin = bf2f(gi[gb + 2 * RNN]);
    }
    hf[b * RNN + j] = h_reg;
}

// ============================================================================
// K3: out[b,o] = h_last[b,:] . fc_w[o,:] + fc_b[o]
// ============================================================================
__global__ __launch_bounds__(256) void out_kernel(
    const float* __restrict__ hf, const float* __restrict__ fc_w,
    const float* __restrict__ fc_b, float* __restrict__ out)
{
    __shared__ float red[256];
    const int bidx = blockIdx.x, tid = threadIdx.x;
    const int o = tid & 3, seg = tid >> 2;
    const float* hp = hf   + (size_t)bidx * RNN + seg * 16;
    const float* wp = fc_w + (size_t)o * RNN + seg * 16;
    float acc = 0.f;
    #pragma unroll
    for (int i = 0; i < 16; ++i) acc += hp[i] * wp[i];
    red[tid] = acc;
    __syncthreads();
    if (tid < 4) {
        float sv = fc_b[tid];
        #pragma unroll 8
        for (int q = 0; q < 64; ++q) sv += red[q * 4 + tid];
        out[bidx * 4 + tid] = sv;
    }
}

extern "C" void kernel_launch(void* const* d_in, const int* in_sizes, int n_in,
                              void* d_out, int out_size, void* d_ws, size_t ws_size,
                              hipStream_t stream)
{
    const int*   x     = (const int*)d_in[0];
    const float* emb   = (const float*)d_in[1];
    const float* w_ih  = (const float*)d_in[2];
    const float* w_hh  = (const float*)d_in[3];
    const float* b_ih  = (const float*)d_in[4];
    const float* b_hh  = (const float*)d_in[5];
    const float* fc_w  = (const float*)d_in[6];
    const float* fc_b  = (const float*)d_in[7];
    float*       out   = (float*)d_out;

    // Fused path needs gi for all 512 steps (201.3 MB); fall back to 4 chunks
    // if the workspace is too small (deterministic per deployment).
    const size_t aux = 2 * (size_t)BATCH * RNN * 2 + (size_t)BATCH * RNN * 4
                     + NGRP * 256 * 4;
    const int tch  = (ws_size >= (size_t)T_TOTAL * BATCH * G3 * 2 + aux) ? 512 : 128;
    const int nchk = T_TOTAL / tch;

    char* ws = (char*)d_ws;
    unsigned short* gi_buf = (unsigned short*)ws;
    size_t off = (size_t)tch * BATCH * G3 * 2;
    unsigned short* hb0 = (unsigned short*)(ws + off); off += (size_t)BATCH * RNN * 2;
    unsigned short* hb1 = (unsigned short*)(ws + off); off += (size_t)BATCH * RNN * 2;
    float*          hf  = (float*)(ws + off);          off += (size_t)BATCH * RNN * 4;
    unsigned int*   bar = (unsigned int*)(ws + off);   // NGRP*256 dwords

    hipFuncSetAttribute((const void*)rec_kernel,
                        hipFuncAttributeMaxDynamicSharedMemorySize, SMEM_BYTES);

    bar_init<<<dim3(1), dim3(256), 0, stream>>>(bar);

    for (int c = 0; c < nchk; ++c) {
        int t0 = c * tch, ns = tch, pb = c * (tch + 1);
        gi_kernel<<<dim3(tch, 48), dim3(256), 0, stream>>>(x, emb, w_ih, b_ih, gi_buf, t0);
        void* args[10];
        args[0] = (void*)&gi_buf; args[1] = (void*)&w_hh; args[2] = (void*)&b_hh;
        args[3] = (void*)&hb0;    args[4] = (void*)&hb1;  args[5] = (void*)&hf;
        args[6] = (void*)&bar;    args[7] = (void*)&t0;   args[8] = (void*)&ns;
        args[9] = (void*)&pb;
        hipLaunchCooperativeKernel((const void*)rec_kernel, dim3(NWG), dim3(256),
                                   args, SMEM_BYTES, stream);
    }
    out_kernel<<<dim3(BATCH), dim3(256), 0, stream>>>(hf, fc_w, fc_b, out);
}

// Round 9
// 2117.167 us; speedup vs baseline: 1.1333x; 1.1333x over previous
//
#include <hip/hip_runtime.h>
#include <hip/hip_bf16.h>

typedef __attribute__((ext_vector_type(8))) short  short8;   // 8 bf16 (4 VGPRs) MFMA frag
typedef __attribute__((ext_vector_type(4))) float  f32x4;    // MFMA accum frag

#define T_TOTAL 512
#define BATCH   64
#define EMB     512
#define RNN     1024
#define G3      3072      // 3*RNN
#define WROWS   48        // 3 gates x 16 units per WG
#define WPAD    1032      // LDS row stride (shorts): 16B-aligned, 2-way bank alias (free)
#define RPAD    18        // red[] batch stride (floats): max 2-way (free)
#define NWG     256
#define NGRP    4         // independent batch groups (16 batches each)
#define NLINE   2         // arrival lines per group (32 WGs each)
#define SMEM_BYTES (WROWS * WPAD * 2 + 4 * WROWS * RPAD * 4)   // 99072 + 13824 = 112896

// ---- bf16 helpers ----
__device__ __forceinline__ unsigned short f2bf(float f) {
    union { float f; unsigned int u; } v; v.f = f;
    unsigned int r = v.u + 0x7fffu + ((v.u >> 16) & 1u);   // round-nearest-even
    return (unsigned short)(r >> 16);
}
__device__ __forceinline__ float bf2f(unsigned short h) {
    union { unsigned int u; float f; } v; v.u = ((unsigned int)h) << 16;
    return v.f;
}
__device__ __forceinline__ float sigmoidf_(float x) { return 1.f / (1.f + __expf(-x)); }
__device__ __forceinline__ float tanhf_(float x) {
    float ax = fabsf(x);
    float e2 = __expf(-2.f * ax);
    float t  = (1.f - e2) / (1.f + e2);
    return x < 0.f ? -t : t;
}

// ============================================================================
// R7 barrier (best measured): split-phase per-group, flag-hop-free.
// Arrive: thread0 RMWs its 32-WG arrival line. Wait: lanes 0/1 poll BOTH
// arrival lines directly (exec-masked spin until each hits 32*ph).
// Release/acquire from per-wave vmcnt order (payload h is itself sc1).
// Counters monotonic across all launches, never reset.
// ============================================================================
__device__ __forceinline__ void gbar_arrive(unsigned int* lines, int lid,
                                            unsigned int ph) {
    __syncthreads();                         // all waves' h stores drained (vmcnt 0)
    if (threadIdx.x == 0)
        __hip_atomic_fetch_add(&lines[lid * 64], 1u,
                               __ATOMIC_RELAXED, __HIP_MEMORY_SCOPE_AGENT);
}
__device__ __forceinline__ void gbar_wait(unsigned int* lines, unsigned int ph) {
    if (threadIdx.x < NLINE) {               // lanes 0,1 of wave 0, exec-masked spin
        while (__hip_atomic_load(&lines[threadIdx.x * 64], __ATOMIC_RELAXED,
                                 __HIP_MEMORY_SCOPE_AGENT) < ph * 32u)
            __builtin_amdgcn_s_sleep(1);
    }
    __syncthreads();
}

__global__ void bar_init(unsigned int* bar) {
    for (int i = threadIdx.x; i < NGRP * 256; i += 256) bar[i] = 0;
}

// ============================================================================
// K1: gi = emb_table[x] @ w_ih^T + b_ih, 128x128 tile (m93 pattern).
// Grid (nrows/128, 24). 4 waves, each 64x64 quadrant = 4x4 accs of 16x16.
// Staging: thread (row=tid>>1, half=tid&1) loads 16 f32 of A (gathered emb
// row) and B (w_ih row), converts to bf16 into 40-padded LDS. BK=32, 16 iters.
// Traffic: 3.1 GB f32 (vs 6.3 at 64x64) — staging-bound, so ~2x faster.
// ============================================================================
__global__ __launch_bounds__(256) void gi_kernel(
    const int* __restrict__ x, const float* __restrict__ emb,
    const float* __restrict__ w_ih, const float* __restrict__ b_ih,
    unsigned short* __restrict__ gi, int t0)
{
    __shared__ __align__(16) unsigned short Asm[128 * 40];
    __shared__ __align__(16) unsigned short Bsm[128 * 40];

    const int tid = threadIdx.x;
    const int m0 = blockIdx.x * 128;        // local row (t_local*64 + b)
    const int n0 = blockIdx.y * 128;

    const int r    = tid >> 1;              // 0..127
    const int half = tid & 1;               // 16-float half of the 32-col chunk
    const int xi = x[t0 * BATCH + m0 + r];  // gather index (global row)
    const float* arow = emb  + (size_t)xi * EMB + half * 16;
    const float* brow = w_ih + (size_t)(n0 + r) * EMB + half * 16;
    unsigned short* adst = &Asm[r * 40 + half * 16];
    unsigned short* bdst = &Bsm[r * 40 + half * 16];

    const int lane = tid & 63, wv = tid >> 6;
    const int m_off = (wv & 1) * 64, n_off = (wv >> 1) * 64;
    const int lr = lane & 15, lq = lane >> 4;

    f32x4 acc[4][4];
    #pragma unroll
    for (int i = 0; i < 4; ++i)
        #pragma unroll
        for (int j = 0; j < 4; ++j) acc[i][j] = (f32x4){0.f, 0.f, 0.f, 0.f};

    for (int k0 = 0; k0 < EMB; k0 += 32) {
        const float4 a0 = *(const float4*)(arow + k0);
        const float4 a1 = *(const float4*)(arow + k0 + 4);
        const float4 a2 = *(const float4*)(arow + k0 + 8);
        const float4 a3 = *(const float4*)(arow + k0 + 12);
        const float4 b0 = *(const float4*)(brow + k0);
        const float4 b1 = *(const float4*)(brow + k0 + 4);
        const float4 b2 = *(const float4*)(brow + k0 + 8);
        const float4 b3 = *(const float4*)(brow + k0 + 12);
        __syncthreads();  // previous iter's frag reads done
        short8 av0, av1, bv0, bv1;
        av0[0]=f2bf(a0.x); av0[1]=f2bf(a0.y); av0[2]=f2bf(a0.z); av0[3]=f2bf(a0.w);
        av0[4]=f2bf(a1.x); av0[5]=f2bf(a1.y); av0[6]=f2bf(a1.z); av0[7]=f2bf(a1.w);
        av1[0]=f2bf(a2.x); av1[1]=f2bf(a2.y); av1[2]=f2bf(a2.z); av1[3]=f2bf(a2.w);
        av1[4]=f2bf(a3.x); av1[5]=f2bf(a3.y); av1[6]=f2bf(a3.z); av1[7]=f2bf(a3.w);
        bv0[0]=f2bf(b0.x); bv0[1]=f2bf(b0.y); bv0[2]=f2bf(b0.z); bv0[3]=f2bf(b0.w);
        bv0[4]=f2bf(b1.x); bv0[5]=f2bf(b1.y); bv0[6]=f2bf(b1.z); bv0[7]=f2bf(b1.w);
        bv1[0]=f2bf(b2.x); bv1[1]=f2bf(b2.y); bv1[2]=f2bf(b2.z); bv1[3]=f2bf(b2.w);
        bv1[4]=f2bf(b3.x); bv1[5]=f2bf(b3.y); bv1[6]=f2bf(b3.z); bv1[7]=f2bf(b3.w);
        *(short8*)(adst)     = av0;
        *(short8*)(adst + 8) = av1;
        *(short8*)(bdst)     = bv0;
        *(short8*)(bdst + 8) = bv1;
        __syncthreads();

        short8 fa[4], fb[4];
        #pragma unroll
        for (int i = 0; i < 4; ++i) {
            fa[i] = *(const short8*)&Asm[(m_off + i * 16 + lr) * 40 + lq * 8];
            fb[i] = *(const short8*)&Bsm[(n_off + i * 16 + lr) * 40 + lq * 8];
        }
        #pragma unroll
        for (int mi = 0; mi < 4; ++mi)
            #pragma unroll
            for (int ni = 0; ni < 4; ++ni)
                acc[mi][ni] = __builtin_amdgcn_mfma_f32_16x16x32_bf16(
                    fa[mi], fb[ni], acc[mi][ni], 0, 0, 0);
    }

    float bia[4];
    #pragma unroll
    for (int ni = 0; ni < 4; ++ni) bia[ni] = b_ih[n0 + n_off + ni * 16 + lr];
    #pragma unroll
    for (int mi = 0; mi < 4; ++mi)
        #pragma unroll
        for (int ni = 0; ni < 4; ++ni) {
            const int n = n0 + n_off + ni * 16 + lr;
            #pragma unroll
            for (int q = 0; q < 4; ++q) {
                const int m = m0 + m_off + mi * 16 + lq * 4 + q;  // C: row=lq*4+q
                gi[(size_t)m * G3 + n] = f2bf(acc[mi][ni][q] + bia[ni]);
            }
        }
}

// ============================================================================
// K2: recurrence (R7 structure — best measured). WG (grp, sidx): batches
// b0=grp*16..+16, units j0=sidx*16..+16; w_hh slice 48 rows in 99 KB dynamic
// LDS. Waves = K quarters, 3 gate-tile MFMAs per k-step. h ping-pong bf16
// sc1; h_reg f32 in-register. Split-phase barrier with gi prefetch under the
// spin. 512 steps fused (or 128/chunk fallback).
// ============================================================================
__global__ __launch_bounds__(256, 1) void rec_kernel(
    const unsigned short* __restrict__ gi,
    const float* __restrict__ w_hh, const float* __restrict__ b_hh,
    unsigned short* __restrict__ hb0, unsigned short* __restrict__ hb1,
    float* __restrict__ hf, unsigned int* bar, int t0, int nsteps, int pbase)
{
    extern __shared__ __align__(16) char smem[];
    unsigned short* Wsm = (unsigned short*)smem;                      // 48 x WPAD
    float (*red)[WROWS][RPAD] = (float (*)[WROWS][RPAD])(smem + WROWS * WPAD * 2);

    const int tid = threadIdx.x;
    const int wg  = blockIdx.x;
    const int grp = wg & 3, sidx = wg >> 2;
    const int b0 = grp * 16, j0 = sidx * 16;
    unsigned int* lines = &bar[grp * 256];          // 2 lines, 256B apart
    const int lid = sidx & (NLINE - 1);

    // ---- stage w_hh slice -> LDS bf16 (rows: [gate*16+u][k]) ----
    #pragma unroll 4
    for (int it = 0; it < 48; ++it) {
        const int i   = it * 256 + tid;
        const int row = i >> 8;                     // 0..47 (256 float4 per row)
        const int c4  = (i & 255) * 4;
        const int gate = row >> 4, uu = row & 15;
        const float4 v = *(const float4*)(w_hh + (size_t)(gate * RNN + j0 + uu) * RNN + c4);
        unsigned short* dst = &Wsm[row * WPAD + c4];
        dst[0] = f2bf(v.x); dst[1] = f2bf(v.y); dst[2] = f2bf(v.z); dst[3] = f2bf(v.w);
    }

    // ---- gate-thread identity: (unit u 0..15, batch bl 0..15) ----
    const int u  = tid & 15;
    const int bl = tid >> 4;
    const int j  = j0 + u;
    const int b  = b0 + bl;
    const float bhr = b_hh[j], bhi = b_hh[RNN + j], bhn = b_hh[2 * RNN + j];

    float h_reg;
    if (t0 == 0) {
        h_reg = 0.f;
        if ((u & 1) == 0)
            __hip_atomic_store((unsigned int*)&hb0[b * RNN + j], 0u,
                               __ATOMIC_RELAXED, __HIP_MEMORY_SCOPE_AGENT);
    } else {
        h_reg = hf[b * RNN + j];            // f32 state from previous launch
    }
    gbar_arrive(lines, lid, (unsigned)(pbase + 1));

    // gi(t=0) prefetch during initial barrier spin (gi is locally indexed)
    size_t gb = (size_t)b * G3 + j0 + u;
    float gir = bf2f(gi[gb]);
    float gii = bf2f(gi[gb + RNN]);
    float gin = bf2f(gi[gb + 2 * RNN]);
    gbar_wait(lines, (unsigned)(pbase + 1));

    // ---- MFMA identity: wave kq = K quarter; lr = batch col / unit row ----
    const int lane = tid & 63, kq = tid >> 6;
    const int lr = lane & 15, lq = lane >> 4;
    const unsigned short* wbase = Wsm + kq * 256 + lq * 8;
    const size_t hoff = ((size_t)(b0 + lr) * RNN + kq * 256 + lq * 8) >> 2;  // in u64s

    for (int t = 0; t < nsteps; ++t) {
        const unsigned short* hrd = (t & 1) ? hb1 : hb0;
        unsigned short*       hwr = (t & 1) ? hb0 : hb1;

        // preload this wave's 16 h u64s (pipelined sc1 MALL reads)
        union { unsigned long long q[2]; short8 s8; } hv[8];
        const unsigned long long* hp = (const unsigned long long*)hrd + hoff;
        #pragma unroll
        for (int ks = 0; ks < 8; ++ks) {
            hv[ks].q[0] = __hip_atomic_load(hp + ks * 8,     __ATOMIC_RELAXED,
                                            __HIP_MEMORY_SCOPE_AGENT);
            hv[ks].q[1] = __hip_atomic_load(hp + ks * 8 + 1, __ATOMIC_RELAXED,
                                            __HIP_MEMORY_SCOPE_AGENT);
        }

        f32x4 acc[3];
        acc[0] = (f32x4){0.f, 0.f, 0.f, 0.f};
        acc[1] = (f32x4){0.f, 0.f, 0.f, 0.f};
        acc[2] = (f32x4){0.f, 0.f, 0.f, 0.f};
        #pragma unroll
        for (int ks = 0; ks < 8; ++ks) {
            const int k = ks * 32;
            #pragma unroll
            for (int gt = 0; gt < 3; ++gt) {
                const short8 a = *(const short8*)(wbase + (gt * 16 + lr) * WPAD + k);
                acc[gt] = __builtin_amdgcn_mfma_f32_16x16x32_bf16(a, hv[ks].s8,
                                                                  acc[gt], 0, 0, 0);
            }
        }
        #pragma unroll
        for (int gt = 0; gt < 3; ++gt)
            #pragma unroll
            for (int q = 0; q < 4; ++q)
                red[kq][gt * 16 + lq * 4 + q][lr] = acc[gt][q];   // C: row=lq*4+q, col=lr
        __syncthreads();

        const float ghr = red[0][u][bl]      + red[1][u][bl]
                        + red[2][u][bl]      + red[3][u][bl];
        const float ghi = red[0][16 + u][bl] + red[1][16 + u][bl]
                        + red[2][16 + u][bl] + red[3][16 + u][bl];
        const float ghn = red[0][32 + u][bl] + red[1][32 + u][bl]
                        + red[2][32 + u][bl] + red[3][32 + u][bl];
        const float rr = sigmoidf_(gir + ghr + bhr);
        const float zz = sigmoidf_(gii + ghi + bhi);
        const float nn = tanhf_(gin + rr * (ghn + bhn));
        h_reg = zz * nn + (1.f - zz) * h_reg;

        // packed pair store (u, u^1 share one dword), write-through sc1
        unsigned int hvv = (unsigned int)f2bf(h_reg);
        unsigned int ovv = __shfl_xor((int)hvv, 1);
        if ((u & 1) == 0)
            __hip_atomic_store((unsigned int*)&hwr[b * RNN + j],
                               hvv | (ovv << 16), __ATOMIC_RELAXED,
                               __HIP_MEMORY_SCOPE_AGENT);

        gbar_arrive(lines, lid, (unsigned)(pbase + 2 + t));
        // prefetch gi(t+1) while the barrier spin is in flight
        const int tn = (t + 1 < nsteps) ? t + 1 : t;
        gb = ((size_t)tn * BATCH + b) * G3 + j0 + u;
        const float ngr = bf2f(gi[gb]);
        const float ngi = bf2f(gi[gb + RNN]);
        const float ngn = bf2f(gi[gb + 2 * RNN]);
        gbar_wait(lines, (unsigned)(pbase + 2 + t));
        gir = ngr; gii = ngi; gin = ngn;
    }
    hf[b * RNN + j] = h_reg;
}

// ============================================================================
// K3: out[b,o] = h_last[b,:] . fc_w[o,:] + fc_b[o]
// ============================================================================
__global__ __launch_bounds__(256) void out_kernel(
    const float* __restrict__ hf, const float* __restrict__ fc_w,
    const float* __restrict__ fc_b, float* __restrict__ out)
{
    __shared__ float red[256];
    const int bidx = blockIdx.x, tid = threadIdx.x;
    const int o = tid & 3, seg = tid >> 2;
    const float* hp = hf   + (size_t)bidx * RNN + seg * 16;
    const float* wp = fc_w + (size_t)o * RNN + seg * 16;
    float acc = 0.f;
    #pragma unroll
    for (int i = 0; i < 16; ++i) acc += hp[i] * wp[i];
    red[tid] = acc;
    __syncthreads();
    if (tid < 4) {
        float sv = fc_b[tid];
        #pragma unroll 8
        for (int q = 0; q < 64; ++q) sv += red[q * 4 + tid];
        out[bidx * 4 + tid] = sv;
    }
}

extern "C" void kernel_launch(void* const* d_in, const int* in_sizes, int n_in,
                              void* d_out, int out_size, void* d_ws, size_t ws_size,
                              hipStream_t stream)
{
    const int*   x     = (const int*)d_in[0];
    const float* emb   = (const float*)d_in[1];
    const float* w_ih  = (const float*)d_in[2];
    const float* w_hh  = (const float*)d_in[3];
    const float* b_ih  = (const float*)d_in[4];
    const float* b_hh  = (const float*)d_in[5];
    const float* fc_w  = (const float*)d_in[6];
    const float* fc_b  = (const float*)d_in[7];
    float*       out   = (float*)d_out;

    // Fused path needs gi for all 512 steps (201.3 MB); fall back to 4 chunks
    // if the workspace is too small (deterministic per deployment).
    const size_t aux = 2 * (size_t)BATCH * RNN * 2 + (size_t)BATCH * RNN * 4
                     + NGRP * 256 * 4;
    const int tch  = (ws_size >= (size_t)T_TOTAL * BATCH * G3 * 2 + aux) ? 512 : 128;
    const int nchk = T_TOTAL / tch;

    char* ws = (char*)d_ws;
    unsigned short* gi_buf = (unsigned short*)ws;
    size_t off = (size_t)tch * BATCH * G3 * 2;
    unsigned short* hb0 = (unsigned short*)(ws + off); off += (size_t)BATCH * RNN * 2;
    unsigned short* hb1 = (unsigned short*)(ws + off); off += (size_t)BATCH * RNN * 2;
    float*          hf  = (float*)(ws + off);          off += (size_t)BATCH * RNN * 4;
    unsigned int*   bar = (unsigned int*)(ws + off);   // NGRP*256 dwords

    hipFuncSetAttribute((const void*)rec_kernel,
                        hipFuncAttributeMaxDynamicSharedMemorySize, SMEM_BYTES);

    bar_init<<<dim3(1), dim3(256), 0, stream>>>(bar);

    for (int c = 0; c < nchk; ++c) {
        int t0 = c * tch, ns = tch, pb = c * (tch + 1);
        gi_kernel<<<dim3(tch * BATCH / 128, 24), dim3(256), 0, stream>>>(
            x, emb, w_ih, b_ih, gi_buf, t0);
        void* args[10];
        args[0] = (void*)&gi_buf; args[1] = (void*)&w_hh; args[2] = (void*)&b_hh;
        args[3] = (void*)&hb0;    args[4] = (void*)&hb1;  args[5] = (void*)&hf;
        args[6] = (void*)&bar;    args[7] = (void*)&t0;   args[8] = (void*)&ns;
        args[9] = (void*)&pb;
        hipLaunchCooperativeKernel((const void*)rec_kernel, dim3(NWG), dim3(256),
                                   args, SMEM_BYTES, stream);
    }
    out_kernel<<<dim3(BATCH), dim3(256), 0, stream>>>(hf, fc_w, fc_b, out);
}